// Round 3
// baseline (380.733 us; speedup 1.0000x reference)
//
#include <hip/hip_runtime.h>
#include <cstddef>
#include <cstdint>

// Problem constants
static constexpr int M_ROWS  = 32768;   // B*T = 64*512
static constexpr int D_INK   = 1024;
static constexpr int D_HID   = 512;
static constexpr int D_CODE_ = 256;
static constexpr int N_CODES_= 128;

static constexpr float TAU_GAP = 0.125f;   // ambiguity threshold for exact-recompute

using bf16x8 = __attribute__((ext_vector_type(8))) __bf16;
using f32x4  = __attribute__((ext_vector_type(4))) float;

// ---------------------------------------------------------------------------
// prep: transpose codebook [128,256] -> cbT [256,128], per-code norms,
// zero loss accumulators + ambiguous-row counter (every call).
// ---------------------------------------------------------------------------
__global__ __launch_bounds__(256)
void prep_cb_kernel(const float* __restrict__ cb, float* __restrict__ cbT,
                    float* __restrict__ cbnorm, float* __restrict__ accum,
                    int* __restrict__ cnt)
{
    const int j = blockIdx.x;      // code index 0..127
    const int t = threadIdx.x;     // dim index 0..255
    const float v = cb[j * D_CODE_ + t];
    cbT[t * N_CODES_ + j] = v;

    __shared__ float sr[256];
    sr[t] = v * v;
    __syncthreads();
    for (int s = 128; s >= 1; s >>= 1) {
        if (t < s) sr[t] += sr[t + s];
        __syncthreads();
    }
    if (t == 0) cbnorm[j] = sr[0];
    if (j == 0 && t < 2) accum[t] = 0.0f;
    if (j == 0 && t == 2) *cnt = 0;
}

// ---------------------------------------------------------------------------
// splitT: W [K][N] fp32 -> WT_hi/WT_lo [N][K] bf16 (hi = rne(bf16), lo = rest)
// grid (K, N/256), 256 threads; coalesced reads, scattered 2B writes (L2-absorbed)
// ---------------------------------------------------------------------------
__global__ __launch_bounds__(256)
void splitT_kernel(const float* __restrict__ W, __bf16* __restrict__ Thi,
                   __bf16* __restrict__ Tlo, int Kd, int Nd)
{
    const int k = blockIdx.x;
    const int n = blockIdx.y * 256 + threadIdx.x;
    const float v = W[(size_t)k * Nd + n];
    const __bf16 hb = (__bf16)v;
    const __bf16 lb = (__bf16)(v - (float)hb);
    Thi[(size_t)n * Kd + k] = hb;
    Tlo[(size_t)n * Kd + k] = lb;
}

// ---------------------------------------------------------------------------
// MFMA GEMM with bf16 hi/lo 3-product split (~fp32 accuracy).
//   C[M,N] = act(A[M,K] @ B[K,N] + bias)
// A: fp32 [M][K] (A_BF16=false) or bf16 pair [M][K] (A_BF16=true)
// B: pre-split transposed bf16 pair [N][K]
// OUT_BF16RELU: relu + write bf16 hi/lo pair; else write fp32.
// 128x128 tile, BK=32, 4 waves (2x2 of 64x64), mfma_f32_16x16x32_bf16.
// LDS frag-linear: frag f=(kg*128+idx) at byte f*16 -> conflict-free r/w.
// ---------------------------------------------------------------------------
template<bool A_BF16, bool OUT_BF16RELU>
__global__ __launch_bounds__(256)
void mfma_gemm_kernel(const float* __restrict__ Af32,
                      const __bf16* __restrict__ Ahi, const __bf16* __restrict__ Alo,
                      const __bf16* __restrict__ BThi, const __bf16* __restrict__ BTlo,
                      const float* __restrict__ bias,
                      float* __restrict__ Cf32,
                      __bf16* __restrict__ Chi, __bf16* __restrict__ Clo,
                      int Kd, int Nd)
{
    __shared__ __align__(16) __bf16 sAh[4096];
    __shared__ __align__(16) __bf16 sAl[4096];
    __shared__ __align__(16) __bf16 sBh[4096];
    __shared__ __align__(16) __bf16 sBl[4096];

    const int tid  = threadIdx.x;
    const int lane = tid & 63;
    const int w    = tid >> 6;
    const int wm   = w >> 1, wn = w & 1;
    const int m0 = blockIdx.x * 128, n0 = blockIdx.y * 128;

    f32x4 acc[4][4];
    #pragma unroll
    for (int i = 0; i < 4; ++i)
        #pragma unroll
        for (int j = 0; j < 4; ++j)
            acc[i][j] = (f32x4){0.f, 0.f, 0.f, 0.f};

    const int kq = lane >> 4;      // 0..3 (k-group within MFMA)
    const int lm = lane & 15;      // row/col within fragment

    for (int k0 = 0; k0 < Kd; k0 += 32) {
        __syncthreads();           // previous iter's LDS reads done
        // ---- stage A (2 frags/thread) + B (2 frags/thread) ----
        #pragma unroll
        for (int s = 0; s < 2; ++s) {
            const int f  = s * 256 + tid;       // 0..511
            const int mi = f & 127;
            const int kg = f >> 7;              // 0..3
            // A
            if (A_BF16) {
                const size_t off = (size_t)(m0 + mi) * Kd + k0 + kg * 8;
                *reinterpret_cast<bf16x8*>(sAh + f * 8) =
                    *reinterpret_cast<const bf16x8*>(Ahi + off);
                *reinterpret_cast<bf16x8*>(sAl + f * 8) =
                    *reinterpret_cast<const bf16x8*>(Alo + off);
            } else {
                const float* sp = Af32 + (size_t)(m0 + mi) * Kd + k0 + kg * 8;
                float vv[8];
                *(float4*)&vv[0] = *(const float4*)(sp);
                *(float4*)&vv[4] = *(const float4*)(sp + 4);
                bf16x8 hf, lf;
                #pragma unroll
                for (int jj = 0; jj < 8; ++jj) {
                    const __bf16 hb = (__bf16)vv[jj];
                    hf[jj] = hb;
                    lf[jj] = (__bf16)(vv[jj] - (float)hb);
                }
                *reinterpret_cast<bf16x8*>(sAh + f * 8) = hf;
                *reinterpret_cast<bf16x8*>(sAl + f * 8) = lf;
            }
            // B (always pre-split bf16, [N][K])
            {
                const size_t off = (size_t)(n0 + mi) * Kd + k0 + kg * 8;
                *reinterpret_cast<bf16x8*>(sBh + f * 8) =
                    *reinterpret_cast<const bf16x8*>(BThi + off);
                *reinterpret_cast<bf16x8*>(sBl + f * 8) =
                    *reinterpret_cast<const bf16x8*>(BTlo + off);
            }
        }
        __syncthreads();           // staged data visible

        // ---- compute ----
        bf16x8 ah[4], al[4];
        #pragma unroll
        for (int fm = 0; fm < 4; ++fm) {
            const int fA = kq * 128 + wm * 64 + fm * 16 + lm;
            ah[fm] = *reinterpret_cast<const bf16x8*>(sAh + fA * 8);
            al[fm] = *reinterpret_cast<const bf16x8*>(sAl + fA * 8);
        }
        #pragma unroll
        for (int fn = 0; fn < 4; ++fn) {
            const int fB = kq * 128 + wn * 64 + fn * 16 + lm;
            const bf16x8 bh = *reinterpret_cast<const bf16x8*>(sBh + fB * 8);
            const bf16x8 bl = *reinterpret_cast<const bf16x8*>(sBl + fB * 8);
            #pragma unroll
            for (int fm = 0; fm < 4; ++fm) {
                acc[fm][fn] = __builtin_amdgcn_mfma_f32_16x16x32_bf16(ah[fm], bh, acc[fm][fn], 0, 0, 0);
                acc[fm][fn] = __builtin_amdgcn_mfma_f32_16x16x32_bf16(al[fm], bh, acc[fm][fn], 0, 0, 0);
                acc[fm][fn] = __builtin_amdgcn_mfma_f32_16x16x32_bf16(ah[fm], bl, acc[fm][fn], 0, 0, 0);
            }
        }
    }

    // ---- epilogue: C/D frag mapping col=lane&15, row=(lane>>4)*4+reg ----
    const int kq4 = kq * 4;
    #pragma unroll
    for (int fn = 0; fn < 4; ++fn) {
        const int col = n0 + wn * 64 + fn * 16 + lm;
        const float bv = bias[col];
        #pragma unroll
        for (int fm = 0; fm < 4; ++fm) {
            #pragma unroll
            for (int r = 0; r < 4; ++r) {
                const int row = m0 + wm * 64 + fm * 16 + kq4 + r;
                float v = acc[fm][fn][r] + bv;
                if (OUT_BF16RELU) {
                    v = fmaxf(v, 0.0f);
                    const __bf16 hb = (__bf16)v;
                    Chi[(size_t)row * Nd + col] = hb;
                    Clo[(size_t)row * Nd + col] = (__bf16)(v - (float)hb);
                } else {
                    Cf32[(size_t)row * Nd + col] = v;
                }
            }
        }
    }
}

// ---------------------------------------------------------------------------
// dist+argmin (fp32): dots = enc @ cbT, argmin_j(cbnorm_j - 2*dot_j) per row.
// Also: second-best gap -> flag ambiguous rows for exact recompute; loss sums.
// ---------------------------------------------------------------------------
__global__ __launch_bounds__(256)
void dist_argmin_kernel(const float* __restrict__ E, const float* __restrict__ CbT,
                        const float* __restrict__ cbnorm,
                        float* __restrict__ outIdx, float* __restrict__ accum,
                        int* __restrict__ cnt, int* __restrict__ list)
{
    __shared__ float As[8][128];
    __shared__ float Bs[8][128];
    __shared__ float sCbn[128];
    __shared__ float sMin[128][17];
    __shared__ float sMin2[128][17];
    __shared__ int   sIdx[128][17];
    __shared__ float sRed[256];

    const int tid = threadIdx.x;
    const int m0 = blockIdx.x * 128;
    const int r0 = (tid >> 4) * 8;
    const int tc = tid & 15;
    const int c0 = tc * 8;

    if (tid < 128) sCbn[tid] = cbnorm[tid];

    const int a_row = tid >> 1;
    const int a_col = (tid & 1) * 4;
    const int b_row = tid >> 5;
    const int b_col = (tid & 31) * 4;

    const float* Ap = E + (size_t)(m0 + a_row) * D_CODE_ + a_col;
    const float* Bp = CbT + (size_t)b_row * N_CODES_ + b_col;

    float acc[8][8];
    #pragma unroll
    for (int i = 0; i < 8; ++i)
        #pragma unroll
        for (int j = 0; j < 8; ++j) acc[i][j] = 0.0f;

    float sumsq = 0.0f;

    for (int k0 = 0; k0 < D_CODE_; k0 += 8) {
        const float4 av = *(const float4*)(Ap + k0);
        const float4 bv = *(const float4*)(Bp + (size_t)k0 * N_CODES_);
        sumsq = fmaf(av.x, av.x, sumsq);
        sumsq = fmaf(av.y, av.y, sumsq);
        sumsq = fmaf(av.z, av.z, sumsq);
        sumsq = fmaf(av.w, av.w, sumsq);
        __syncthreads();
        As[a_col + 0][a_row] = av.x;
        As[a_col + 1][a_row] = av.y;
        As[a_col + 2][a_row] = av.z;
        As[a_col + 3][a_row] = av.w;
        *(float4*)(&Bs[b_row][b_col]) = bv;
        __syncthreads();
        #pragma unroll
        for (int kk = 0; kk < 8; ++kk) {
            float a[8], b[8];
            *(float4*)(&a[0]) = *(const float4*)(&As[kk][r0]);
            *(float4*)(&a[4]) = *(const float4*)(&As[kk][r0 + 4]);
            *(float4*)(&b[0]) = *(const float4*)(&Bs[kk][c0]);
            *(float4*)(&b[4]) = *(const float4*)(&Bs[kk][c0 + 4]);
            #pragma unroll
            for (int i = 0; i < 8; ++i)
                #pragma unroll
                for (int j = 0; j < 8; ++j)
                    acc[i][j] = fmaf(a[i], b[j], acc[i][j]);
        }
    }

    // per-thread best + second-best over its 8 codes (ascending -> first-min)
    #pragma unroll
    for (int i = 0; i < 8; ++i) {
        float b1 = 3.4e38f, b2 = 3.4e38f;
        int bj = 0;
        #pragma unroll
        for (int j = 0; j < 8; ++j) {
            const float v = fmaf(-2.0f, acc[i][j], sCbn[c0 + j]);
            if (v < b1) { b2 = b1; b1 = v; bj = c0 + j; }
            else if (v < b2) b2 = v;
        }
        sMin[r0 + i][tc]  = b1;
        sMin2[r0 + i][tc] = b2;
        sIdx[r0 + i][tc]  = bj;
    }
    __syncthreads();

    float rowVal = 0.0f;
    if (tid < 128) {
        float B1 = 3.4e38f, B2 = 3.4e38f;
        int I1 = 0;
        #pragma unroll
        for (int t2 = 0; t2 < 16; ++t2) {
            const float p1 = sMin[tid][t2];
            const float p2 = sMin2[tid][t2];
            if (p1 < B1) { B2 = fminf(B1, p2); B1 = p1; I1 = sIdx[tid][t2]; }
            else         { B2 = fminf(B2, p1); }
        }
        outIdx[m0 + tid] = (float)I1;
        rowVal = B1;
        if (B2 - B1 < TAU_GAP) {              // ambiguous under bf16x3 jitter
            const int pos = atomicAdd(cnt, 1);
            list[pos] = m0 + tid;
        }
    }

    sRed[tid] = (tid < 128) ? rowVal : 0.0f;
    __syncthreads();
    for (int s = 128; s >= 1; s >>= 1) {
        if (tid < s) sRed[tid] += sRed[tid + s];
        __syncthreads();
    }
    const float minSum = sRed[0];
    __syncthreads();
    sRed[tid] = sumsq;
    __syncthreads();
    for (int s = 128; s >= 1; s >>= 1) {
        if (tid < s) sRed[tid] += sRed[tid + s];
        __syncthreads();
    }
    if (tid == 0) {
        atomicAdd(&accum[0], minSum);
        atomicAdd(&accum[1], sRed[0]);
    }
}

// ---------------------------------------------------------------------------
// fixup: exact fp32 recompute of flagged (near-tie) rows; overwrite index.
// ---------------------------------------------------------------------------
__global__ __launch_bounds__(256)
void fixup_kernel(const float* __restrict__ x, const float* __restrict__ W1,
                  const float* __restrict__ b1, const float* __restrict__ W2,
                  const float* __restrict__ b2, const float* __restrict__ cb,
                  const float* __restrict__ cbnorm,
                  const int* __restrict__ cnt, const int* __restrict__ list,
                  float* __restrict__ outIdx)
{
    __shared__ float xr[1024];
    __shared__ float hr[512];
    __shared__ float er[256];
    __shared__ float dv[128];
    __shared__ int   di[128];

    const int tid = threadIdx.x;
    const int n = *cnt;
    for (int it = blockIdx.x; it < n; it += gridDim.x) {
        const int row = list[it];
        __syncthreads();   // LDS reuse guard across iterations
        #pragma unroll
        for (int i = 0; i < 4; ++i)
            xr[tid + i * 256] = x[(size_t)row * D_INK + tid + i * 256];
        __syncthreads();
        // h = relu(x_row @ W1 + b1): 2 cols/thread
        {
            const int c = tid * 2;
            float s0 = 0.f, s1 = 0.f;
            for (int k = 0; k < D_INK; ++k) {
                const float xv = xr[k];
                const float2 wv = *(const float2*)(W1 + (size_t)k * D_HID + c);
                s0 = fmaf(xv, wv.x, s0);
                s1 = fmaf(xv, wv.y, s1);
            }
            hr[c]     = fmaxf(s0 + b1[c], 0.f);
            hr[c + 1] = fmaxf(s1 + b1[c + 1], 0.f);
        }
        __syncthreads();
        // enc = h @ W2 + b2: 1 col/thread
        {
            float s = 0.f;
            for (int k = 0; k < D_HID; ++k)
                s = fmaf(hr[k], W2[(size_t)k * D_CODE_ + tid], s);
            er[tid] = s + b2[tid];
        }
        __syncthreads();
        // distances in reference expanded form: (e2 - 2*dot) + cbnorm
        if (tid < 128) {
            float e2 = 0.f;
            for (int k = 0; k < D_CODE_; ++k) e2 = fmaf(er[k], er[k], e2);
            float dot = 0.f;
            const float* cr = cb + (size_t)tid * D_CODE_;
            for (int k = 0; k < D_CODE_; ++k) dot = fmaf(er[k], cr[k], dot);
            dv[tid] = (e2 - 2.0f * dot) + cbnorm[tid];
            di[tid] = tid;
        }
        __syncthreads();
        for (int st = 64; st >= 1; st >>= 1) {
            if (tid < st) {
                const float a = dv[tid], b = dv[tid + st];
                const int  ib = di[tid + st];
                if (b < a || (b == a && ib < di[tid])) { dv[tid] = b; di[tid] = ib; }
            }
            __syncthreads();
        }
        if (tid == 0) outIdx[row] = (float)di[0];
    }
}

// ---------------------------------------------------------------------------
__global__ void finalize_kernel(const float* __restrict__ accum, float* __restrict__ out)
{
    const float inv = 1.0f / (32768.0f * 256.0f);
    const float loss = (accum[0] + accum[1]) * inv;   // commitment == codebook
    out[32768] = loss;
    out[32769] = loss;
    out[32770] = 1.25f * loss;
}

// ---------------------------------------------------------------------------
extern "C" void kernel_launch(void* const* d_in, const int* in_sizes, int n_in,
                              void* d_out, int out_size, void* d_ws, size_t ws_size,
                              hipStream_t stream)
{
    (void)in_sizes; (void)n_in; (void)out_size; (void)ws_size;

    const float* x  = (const float*)d_in[0];  // [32768,1024]
    const float* W1 = (const float*)d_in[1];  // [1024,512]
    const float* b1 = (const float*)d_in[2];  // [512]
    const float* W2 = (const float*)d_in[3];  // [512,256]
    const float* b2 = (const float*)d_in[4];  // [256]
    const float* cb = (const float*)d_in[5];  // [128,256]
    float* out = (float*)d_out;

    // workspace layout (bytes)
    char* ws = (char*)d_ws;
    __bf16* W1Thi = (__bf16*)(ws + 0);                    // 1 MB
    __bf16* W1Tlo = (__bf16*)(ws + 1048576);              // 1 MB
    __bf16* W2Thi = (__bf16*)(ws + 2097152);              // 256 KB
    __bf16* W2Tlo = (__bf16*)(ws + 2359296);              // 256 KB
    __bf16* h_hi  = (__bf16*)(ws + 4194304);              // 32 MB
    __bf16* h_lo  = (__bf16*)(ws + 37748736);             // 32 MB
    float*  enc   = (float* )(ws + 71303168);             // 32 MB
    float*  cbT   = (float* )(ws + 104857600);            // 128 KB
    float*  cbn   = (float* )(ws + 104988672);            // 512 B
    float*  accum = (float* )(ws + 104989184);            // 64 B
    int*    cnt   = (int*  )(ws + 104989248);             // 64 B
    int*    list  = (int*  )(ws + 104989312);             // 128 KB

    prep_cb_kernel<<<N_CODES_, 256, 0, stream>>>(cb, cbT, cbn, accum, cnt);
    splitT_kernel<<<dim3(D_INK, D_HID / 256), 256, 0, stream>>>(W1, W1Thi, W1Tlo, D_INK, D_HID);
    splitT_kernel<<<dim3(D_HID, D_CODE_ / 256), 256, 0, stream>>>(W2, W2Thi, W2Tlo, D_HID, D_CODE_);

    // h(hi/lo) = relu(x @ W1 + b1)   M=32768 K=1024 N=512
    mfma_gemm_kernel<false, true><<<dim3(M_ROWS / 128, D_HID / 128), 256, 0, stream>>>(
        x, nullptr, nullptr, W1Thi, W1Tlo, b1, nullptr, h_hi, h_lo, D_INK, D_HID);
    // enc = h @ W2 + b2              M=32768 K=512  N=256
    mfma_gemm_kernel<true, false><<<dim3(M_ROWS / 128, D_CODE_ / 128), 256, 0, stream>>>(
        nullptr, h_hi, h_lo, W2Thi, W2Tlo, b2, enc, nullptr, nullptr, D_HID, D_CODE_);

    dist_argmin_kernel<<<M_ROWS / 128, 256, 0, stream>>>(enc, cbT, cbn, out, accum, cnt, list);
    fixup_kernel<<<256, 256, 0, stream>>>(x, W1, b1, W2, b2, cb, cbn, cnt, list, out);
    finalize_kernel<<<1, 1, 0, stream>>>(accum, out);
}

// Round 4
// 345.260 us; speedup vs baseline: 1.1027x; 1.1027x over previous
//
#include <hip/hip_runtime.h>
#include <cstddef>
#include <cstdint>

// Problem constants
static constexpr int M_ROWS  = 32768;   // B*T
static constexpr int D_INK   = 1024;
static constexpr int D_HID   = 512;
static constexpr int D_CODE_ = 256;
static constexpr int N_CODES_= 128;

static constexpr float TAU_GAP = 0.125f;   // ambiguity threshold for exact-recompute

using bf16x8 = __attribute__((ext_vector_type(8))) __bf16;
using f32x4  = __attribute__((ext_vector_type(4))) float;

// ---------------------------------------------------------------------------
// direct global->LDS DMA, 16 B per lane (dest = wave-uniform base + lane*16)
// ---------------------------------------------------------------------------
__device__ __forceinline__ void dma16(const void* g, void* l) {
    __builtin_amdgcn_global_load_lds(
        (const __attribute__((address_space(1))) void*)g,
        (__attribute__((address_space(3))) void*)l, 16, 0, 0);
}

// stage a [128 rows x 32 k] bf16 hi/lo tile into LDS, frag-linear:
// frag f = kq*128 + rc  holds  src[row0+rc][k0 + kq*8 .. +8]  at elem offset f*8.
// 8 DMA instructions per array, split 2 per wave (w = 0..3).
__device__ __forceinline__ void stage_pair_dma(const __bf16* __restrict__ hi,
                                               const __bf16* __restrict__ lo,
                                               __bf16* shi, __bf16* slo,
                                               int w, int lane, int row0, int stride, int k0)
{
    #pragma unroll
    for (int ii = 0; ii < 2; ++ii) {
        const int I  = 2 * w + ii;          // 0..7
        const int f  = I * 64 + lane;       // frag 0..511
        const int rc = f & 127;
        const int kq = f >> 7;
        const size_t go = (size_t)(row0 + rc) * stride + k0 + kq * 8;
        dma16(hi + go, shi + (size_t)I * 512);
        dma16(lo + go, slo + (size_t)I * 512);
    }
}

// one BK=32 compute step: 4x4 fragment tile per wave, 3-product hi/lo split
__device__ __forceinline__ void mfma_tile(const __bf16* sAh, const __bf16* sAl,
                                          const __bf16* sBh, const __bf16* sBl,
                                          int wm, int wn, int kq, int lm,
                                          f32x4 (&acc)[4][4])
{
    bf16x8 ah[4], al[4];
    #pragma unroll
    for (int fm = 0; fm < 4; ++fm) {
        const int fA = kq * 128 + wm * 64 + fm * 16 + lm;
        ah[fm] = *(const bf16x8*)(sAh + fA * 8);
        al[fm] = *(const bf16x8*)(sAl + fA * 8);
    }
    #pragma unroll
    for (int fn = 0; fn < 4; ++fn) {
        const int fB = kq * 128 + wn * 64 + fn * 16 + lm;
        const bf16x8 bh = *(const bf16x8*)(sBh + fB * 8);
        const bf16x8 bl = *(const bf16x8*)(sBl + fB * 8);
        #pragma unroll
        for (int fm = 0; fm < 4; ++fm) {
            acc[fm][fn] = __builtin_amdgcn_mfma_f32_16x16x32_bf16(ah[fm], bh, acc[fm][fn], 0, 0, 0);
            acc[fm][fn] = __builtin_amdgcn_mfma_f32_16x16x32_bf16(al[fm], bh, acc[fm][fn], 0, 0, 0);
            acc[fm][fn] = __builtin_amdgcn_mfma_f32_16x16x32_bf16(ah[fm], bl, acc[fm][fn], 0, 0, 0);
        }
    }
}

// ---------------------------------------------------------------------------
// prep: split codebook to hi/lo bf16 (layout [code][k] == B-operand layout),
// exact per-code norms, zero accumulators.
// ---------------------------------------------------------------------------
__global__ __launch_bounds__(256)
void prep_cb_kernel(const float* __restrict__ cb, __bf16* __restrict__ cbhi,
                    __bf16* __restrict__ cblo, float* __restrict__ cbnorm,
                    float* __restrict__ accum, int* __restrict__ cnt)
{
    const int j = blockIdx.x;      // code 0..127
    const int t = threadIdx.x;     // dim 0..255
    const float v = cb[j * D_CODE_ + t];
    const __bf16 hb = (__bf16)v;
    cbhi[j * D_CODE_ + t] = hb;
    cblo[j * D_CODE_ + t] = (__bf16)(v - (float)hb);

    __shared__ float sr[256];
    sr[t] = v * v;
    __syncthreads();
    for (int s = 128; s >= 1; s >>= 1) {
        if (t < s) sr[t] += sr[t + s];
        __syncthreads();
    }
    if (t == 0) cbnorm[j] = sr[0];
    if (j == 0 && t < 2) accum[t] = 0.0f;
    if (j == 0 && t == 2) *cnt = 0;
}

// ---------------------------------------------------------------------------
// splitT: W [K][N] fp32 -> WT_hi/WT_lo [N][K] bf16
// ---------------------------------------------------------------------------
__global__ __launch_bounds__(256)
void splitT_kernel(const float* __restrict__ W, __bf16* __restrict__ Thi,
                   __bf16* __restrict__ Tlo, int Kd, int Nd)
{
    const int k = blockIdx.x;
    const int n = blockIdx.y * 256 + threadIdx.x;
    const float v = W[(size_t)k * Nd + n];
    const __bf16 hb = (__bf16)v;
    Thi[(size_t)n * Kd + k] = hb;
    Tlo[(size_t)n * Kd + k] = (__bf16)(v - (float)hb);
}

// ---------------------------------------------------------------------------
// GEMM1: h(hi/lo) = relu(x @ W1 + b1).  A fp32 converted in-register;
// B via global_load_lds.  Double-buffered LDS, ONE barrier per K-step.
// ---------------------------------------------------------------------------
__global__ __launch_bounds__(256)
void gemm1_kernel(const float* __restrict__ X,
                  const __bf16* __restrict__ BThi, const __bf16* __restrict__ BTlo,
                  const float* __restrict__ bias,
                  __bf16* __restrict__ Chi, __bf16* __restrict__ Clo)
{
    __shared__ __bf16 lds[2][4][4096];     // [buf][Ah,Al,Bh,Bl][frag elems]

    const int tid  = threadIdx.x;
    const int lane = tid & 63;
    const int w    = tid >> 6;
    const int wm = w >> 1, wn = w & 1;
    const int kq = lane >> 4, lm = lane & 15;
    const int m0 = blockIdx.x * 128, n0 = blockIdx.y * 128;

    f32x4 acc[4][4] = {};

    // this thread converts frags f0 = tid, f1 = tid+256
    const int f0 = tid, f1 = tid + 256;
    const float* xp0 = X + (size_t)(m0 + (f0 & 127)) * D_INK + (f0 >> 7) * 8;
    const float* xp1 = X + (size_t)(m0 + (f1 & 127)) * D_INK + (f1 >> 7) * 8;

    // prologue: stage step 0 into buf 0
    {
        float a0[8], a1[8];
        *(float4*)&a0[0] = *(const float4*)(xp0);     *(float4*)&a0[4] = *(const float4*)(xp0 + 4);
        *(float4*)&a1[0] = *(const float4*)(xp1);     *(float4*)&a1[4] = *(const float4*)(xp1 + 4);
        stage_pair_dma(BThi, BTlo, &lds[0][2][0], &lds[0][3][0], w, lane, n0, D_INK, 0);
        bf16x8 h8, l8;
        #pragma unroll
        for (int j = 0; j < 8; ++j) { const __bf16 hb = (__bf16)a0[j]; h8[j] = hb; l8[j] = (__bf16)(a0[j] - (float)hb); }
        *(bf16x8*)(&lds[0][0][0] + f0 * 8) = h8;   *(bf16x8*)(&lds[0][1][0] + f0 * 8) = l8;
        #pragma unroll
        for (int j = 0; j < 8; ++j) { const __bf16 hb = (__bf16)a1[j]; h8[j] = hb; l8[j] = (__bf16)(a1[j] - (float)hb); }
        *(bf16x8*)(&lds[0][0][0] + f1 * 8) = h8;   *(bf16x8*)(&lds[0][1][0] + f1 * 8) = l8;
    }

    constexpr int NSTEP = D_INK / 32;
    for (int t = 0; t < NSTEP; ++t) {
        const int cur = t & 1, nxt = cur ^ 1;
        __syncthreads();                               // drain: buf[cur] ready, buf[nxt] free
        float a0[8], a1[8];
        const bool more = (t + 1) < NSTEP;
        if (more) {
            const int k0n = (t + 1) * 32;
            *(float4*)&a0[0] = *(const float4*)(xp0 + k0n);  *(float4*)&a0[4] = *(const float4*)(xp0 + k0n + 4);
            *(float4*)&a1[0] = *(const float4*)(xp1 + k0n);  *(float4*)&a1[4] = *(const float4*)(xp1 + k0n + 4);
            stage_pair_dma(BThi, BTlo, &lds[nxt][2][0], &lds[nxt][3][0], w, lane, n0, D_INK, k0n);
        }
        mfma_tile(&lds[cur][0][0], &lds[cur][1][0], &lds[cur][2][0], &lds[cur][3][0],
                  wm, wn, kq, lm, acc);
        if (more) {
            bf16x8 h8, l8;
            #pragma unroll
            for (int j = 0; j < 8; ++j) { const __bf16 hb = (__bf16)a0[j]; h8[j] = hb; l8[j] = (__bf16)(a0[j] - (float)hb); }
            *(bf16x8*)(&lds[nxt][0][0] + f0 * 8) = h8;   *(bf16x8*)(&lds[nxt][1][0] + f0 * 8) = l8;
            #pragma unroll
            for (int j = 0; j < 8; ++j) { const __bf16 hb = (__bf16)a1[j]; h8[j] = hb; l8[j] = (__bf16)(a1[j] - (float)hb); }
            *(bf16x8*)(&lds[nxt][0][0] + f1 * 8) = h8;   *(bf16x8*)(&lds[nxt][1][0] + f1 * 8) = l8;
        }
    }

    // epilogue: relu + hi/lo split store (C/D: col = lane&15, row = kq*4 + r)
    #pragma unroll
    for (int fn = 0; fn < 4; ++fn) {
        const int col = n0 + wn * 64 + fn * 16 + lm;
        const float bv = bias[col];
        #pragma unroll
        for (int fm = 0; fm < 4; ++fm) {
            #pragma unroll
            for (int r = 0; r < 4; ++r) {
                const int row = m0 + wm * 64 + fm * 16 + kq * 4 + r;
                const float v = fmaxf(acc[fm][fn][r] + bv, 0.0f);
                const __bf16 hb = (__bf16)v;
                Chi[(size_t)row * D_HID + col] = hb;
                Clo[(size_t)row * D_HID + col] = (__bf16)(v - (float)hb);
            }
        }
    }
}

// ---------------------------------------------------------------------------
// GEMM2: enc(hi/lo) = h @ W2 + b2, plus sum(enc^2) atomic.  All-DMA staging.
// ---------------------------------------------------------------------------
__global__ __launch_bounds__(256)
void gemm2_kernel(const __bf16* __restrict__ Ahi, const __bf16* __restrict__ Alo,
                  const __bf16* __restrict__ BThi, const __bf16* __restrict__ BTlo,
                  const float* __restrict__ bias,
                  __bf16* __restrict__ Chi, __bf16* __restrict__ Clo,
                  float* __restrict__ accum)
{
    __shared__ __bf16 lds[2][4][4096];

    const int tid  = threadIdx.x;
    const int lane = tid & 63;
    const int w    = tid >> 6;
    const int wm = w >> 1, wn = w & 1;
    const int kq = lane >> 4, lm = lane & 15;
    const int m0 = blockIdx.x * 128, n0 = blockIdx.y * 128;

    f32x4 acc[4][4] = {};

    stage_pair_dma(Ahi, Alo, &lds[0][0][0], &lds[0][1][0], w, lane, m0, D_HID, 0);
    stage_pair_dma(BThi, BTlo, &lds[0][2][0], &lds[0][3][0], w, lane, n0, D_HID, 0);

    constexpr int NSTEP = D_HID / 32;
    for (int t = 0; t < NSTEP; ++t) {
        const int cur = t & 1, nxt = cur ^ 1;
        __syncthreads();
        if (t + 1 < NSTEP) {
            const int k0n = (t + 1) * 32;
            stage_pair_dma(Ahi, Alo, &lds[nxt][0][0], &lds[nxt][1][0], w, lane, m0, D_HID, k0n);
            stage_pair_dma(BThi, BTlo, &lds[nxt][2][0], &lds[nxt][3][0], w, lane, n0, D_HID, k0n);
        }
        mfma_tile(&lds[cur][0][0], &lds[cur][1][0], &lds[cur][2][0], &lds[cur][3][0],
                  wm, wn, kq, lm, acc);
    }

    float sumsq = 0.0f;
    #pragma unroll
    for (int fn = 0; fn < 4; ++fn) {
        const int col = n0 + wn * 64 + fn * 16 + lm;
        const float bv = bias[col];
        #pragma unroll
        for (int fm = 0; fm < 4; ++fm) {
            #pragma unroll
            for (int r = 0; r < 4; ++r) {
                const int row = m0 + wm * 64 + fm * 16 + kq * 4 + r;
                const float v = acc[fm][fn][r] + bv;
                sumsq = fmaf(v, v, sumsq);
                const __bf16 hb = (__bf16)v;
                Chi[(size_t)row * D_CODE_ + col] = hb;
                Clo[(size_t)row * D_CODE_ + col] = (__bf16)(v - (float)hb);
            }
        }
    }
    #pragma unroll
    for (int mk = 1; mk <= 32; mk <<= 1) sumsq += __shfl_xor(sumsq, mk);
    if (lane == 0) atomicAdd(&accum[1], sumsq);
}

// ---------------------------------------------------------------------------
// dist: dots = enc @ cb^T via MFMA (BN=128 = all codes); epilogue argmin with
// second-best gap flagging + min-term loss sum.
// ---------------------------------------------------------------------------
__global__ __launch_bounds__(256)
void dist_kernel(const __bf16* __restrict__ Ehi, const __bf16* __restrict__ Elo,
                 const __bf16* __restrict__ CBhi, const __bf16* __restrict__ CBlo,
                 const float* __restrict__ cbn,
                 float* __restrict__ outIdx, float* __restrict__ accum,
                 int* __restrict__ cnt, int* __restrict__ list)
{
    __shared__ __bf16 lds[2][4][4096];

    const int tid  = threadIdx.x;
    const int lane = tid & 63;
    const int w    = tid >> 6;
    const int wm = w >> 1, wn = w & 1;
    const int kq = lane >> 4, lm = lane & 15;
    const int m0 = blockIdx.x * 128;

    float cbn_l[4];
    #pragma unroll
    for (int fn = 0; fn < 4; ++fn) cbn_l[fn] = cbn[wn * 64 + fn * 16 + lm];

    f32x4 acc[4][4] = {};

    stage_pair_dma(Ehi, Elo, &lds[0][0][0], &lds[0][1][0], w, lane, m0, D_CODE_, 0);
    stage_pair_dma(CBhi, CBlo, &lds[0][2][0], &lds[0][3][0], w, lane, 0, D_CODE_, 0);

    constexpr int NSTEP = D_CODE_ / 32;
    for (int t = 0; t < NSTEP; ++t) {
        const int cur = t & 1, nxt = cur ^ 1;
        __syncthreads();
        if (t + 1 < NSTEP) {
            const int k0n = (t + 1) * 32;
            stage_pair_dma(Ehi, Elo, &lds[nxt][0][0], &lds[nxt][1][0], w, lane, m0, D_CODE_, k0n);
            stage_pair_dma(CBhi, CBlo, &lds[nxt][2][0], &lds[nxt][3][0], w, lane, 0, D_CODE_, k0n);
        }
        mfma_tile(&lds[cur][0][0], &lds[cur][1][0], &lds[cur][2][0], &lds[cur][3][0],
                  wm, wn, kq, lm, acc);
    }

    __syncthreads();   // all LDS reads done before reuse as epilogue scratch
    float* eb1 = (float*)&lds[0][0][0];        // [2][128]
    float* eb2 = eb1 + 256;
    int*   eix = (int*)(eb2 + 256);

    // per-lane best/second over this wave's 64 codes, per owned row
    #pragma unroll
    for (int fm = 0; fm < 4; ++fm) {
        #pragma unroll
        for (int r = 0; r < 4; ++r) {
            float b1v = 3.4e38f, b2v = 3.4e38f; int bi = 0;
            #pragma unroll
            for (int fn = 0; fn < 4; ++fn) {
                const float v = fmaf(-2.0f, acc[fm][fn][r], cbn_l[fn]);
                if (v < b1v) { b2v = b1v; b1v = v; bi = wn * 64 + fn * 16 + lm; }
                else if (v < b2v) b2v = v;
            }
            // reduce across the 16 lanes (lm) of this kq group
            #pragma unroll
            for (int mk = 1; mk <= 8; mk <<= 1) {
                const float o1 = __shfl_xor(b1v, mk);
                const float o2 = __shfl_xor(b2v, mk);
                const int   oi = __shfl_xor(bi,  mk);
                if (o1 < b1v || (o1 == b1v && oi < bi)) { b2v = fminf(b1v, o2); b1v = o1; bi = oi; }
                else b2v = fminf(b2v, o1);
            }
            const int rl = wm * 64 + fm * 16 + kq * 4 + r;
            if (lm == 0) { eb1[wn * 128 + rl] = b1v; eb2[wn * 128 + rl] = b2v; eix[wn * 128 + rl] = bi; }
        }
    }
    __syncthreads();

    if (tid < 128) {
        const int rl = tid;
        const float a1 = eb1[rl], a2 = eb2[rl]; const int ai = eix[rl];
        const float o1 = eb1[128 + rl], o2 = eb2[128 + rl]; const int oi = eix[128 + rl];
        float B1, B2; int BI;
        if (o1 < a1 || (o1 == a1 && oi < ai)) { B1 = o1; BI = oi; B2 = fminf(a1, o2); }
        else                                  { B1 = a1; BI = ai; B2 = fminf(a2, o1); }
        outIdx[m0 + rl] = (float)BI;
        if (B2 - B1 < TAU_GAP) { const int p = atomicAdd(cnt, 1); list[p] = m0 + rl; }
        float s = B1;
        #pragma unroll
        for (int mk = 1; mk <= 32; mk <<= 1) s += __shfl_xor(s, mk);
        if (lane == 0) atomicAdd(&accum[0], s);
    }
}

// ---------------------------------------------------------------------------
// fixup: exact fp32 recompute of flagged (near-tie) rows; overwrite index.
// ---------------------------------------------------------------------------
__global__ __launch_bounds__(256)
void fixup_kernel(const float* __restrict__ x, const float* __restrict__ W1,
                  const float* __restrict__ b1, const float* __restrict__ W2,
                  const float* __restrict__ b2, const float* __restrict__ cb,
                  const float* __restrict__ cbnorm,
                  const int* __restrict__ cnt, const int* __restrict__ list,
                  float* __restrict__ outIdx)
{
    __shared__ float xr[1024];
    __shared__ float hr[512];
    __shared__ float er[256];
    __shared__ float dv[128];
    __shared__ int   di[128];

    const int tid = threadIdx.x;
    const int n = *cnt;
    for (int it = blockIdx.x; it < n; it += gridDim.x) {
        const int row = list[it];
        __syncthreads();
        #pragma unroll
        for (int i = 0; i < 4; ++i)
            xr[tid + i * 256] = x[(size_t)row * D_INK + tid + i * 256];
        __syncthreads();
        {
            const int c = tid * 2;
            float s0 = 0.f, s1 = 0.f;
            for (int k = 0; k < D_INK; ++k) {
                const float xv = xr[k];
                const float2 wv = *(const float2*)(W1 + (size_t)k * D_HID + c);
                s0 = fmaf(xv, wv.x, s0);
                s1 = fmaf(xv, wv.y, s1);
            }
            hr[c]     = fmaxf(s0 + b1[c], 0.f);
            hr[c + 1] = fmaxf(s1 + b1[c + 1], 0.f);
        }
        __syncthreads();
        {
            float s = 0.f;
            for (int k = 0; k < D_HID; ++k)
                s = fmaf(hr[k], W2[(size_t)k * D_CODE_ + tid], s);
            er[tid] = s + b2[tid];
        }
        __syncthreads();
        if (tid < 128) {
            float e2 = 0.f;
            for (int k = 0; k < D_CODE_; ++k) e2 = fmaf(er[k], er[k], e2);
            float dot = 0.f;
            const float* cr = cb + (size_t)tid * D_CODE_;
            for (int k = 0; k < D_CODE_; ++k) dot = fmaf(er[k], cr[k], dot);
            dv[tid] = (e2 - 2.0f * dot) + cbnorm[tid];
            di[tid] = tid;
        }
        __syncthreads();
        for (int st = 64; st >= 1; st >>= 1) {
            if (tid < st) {
                const float a = dv[tid], b = dv[tid + st];
                const int  ib = di[tid + st];
                if (b < a || (b == a && ib < di[tid])) { dv[tid] = b; di[tid] = ib; }
            }
            __syncthreads();
        }
        if (tid == 0) outIdx[row] = (float)di[0];
    }
}

// ---------------------------------------------------------------------------
__global__ void finalize_kernel(const float* __restrict__ accum, float* __restrict__ out)
{
    const float inv = 1.0f / (32768.0f * 256.0f);
    const float loss = (accum[0] + accum[1]) * inv;   // commitment == codebook
    out[32768] = loss;
    out[32769] = loss;
    out[32770] = 1.25f * loss;
}

// ---------------------------------------------------------------------------
extern "C" void kernel_launch(void* const* d_in, const int* in_sizes, int n_in,
                              void* d_out, int out_size, void* d_ws, size_t ws_size,
                              hipStream_t stream)
{
    (void)in_sizes; (void)n_in; (void)out_size; (void)ws_size;

    const float* x  = (const float*)d_in[0];  // [32768,1024]
    const float* W1 = (const float*)d_in[1];  // [1024,512]
    const float* b1 = (const float*)d_in[2];  // [512]
    const float* W2 = (const float*)d_in[3];  // [512,256]
    const float* b2 = (const float*)d_in[4];  // [256]
    const float* cb = (const float*)d_in[5];  // [128,256]
    float* out = (float*)d_out;

    // workspace layout (bytes)
    char* ws = (char*)d_ws;
    __bf16* W1Thi = (__bf16*)(ws + 0);                    // 1 MB  [512][1024]
    __bf16* W1Tlo = (__bf16*)(ws + (1u<<20));             // 1 MB
    __bf16* W2Thi = (__bf16*)(ws + (2u<<20));             // 256 KB [256][512]
    __bf16* W2Tlo = (__bf16*)(ws + (2u<<20) + 262144);    // 256 KB
    __bf16* cbhi  = (__bf16*)(ws + (2u<<20) + 524288);    // 64 KB  [128][256]
    __bf16* cblo  = (__bf16*)(ws + (2u<<20) + 589824);    // 64 KB
    float*  cbn   = (float* )(ws + (2u<<20) + 655360);    // 512 B
    float*  accum = (float* )(ws + (2u<<20) + 655872);    // 64 B
    int*    cnt   = (int*   )(ws + (2u<<20) + 655936);    // 64 B
    int*    list  = (int*   )(ws + (2u<<20) + 656000);    // 128 KB
    __bf16* h_hi  = (__bf16*)(ws + (size_t)(4u<<20));             // 32 MB
    __bf16* h_lo  = (__bf16*)(ws + (size_t)(4u<<20) + 33554432);  // 32 MB
    __bf16* enchi = (__bf16*)(ws + (size_t)(4u<<20) + 67108864);  // 16 MB
    __bf16* enclo = (__bf16*)(ws + (size_t)(4u<<20) + 83886080);  // 16 MB

    prep_cb_kernel<<<N_CODES_, 256, 0, stream>>>(cb, cbhi, cblo, cbn, accum, cnt);
    splitT_kernel<<<dim3(D_INK, D_HID / 256), 256, 0, stream>>>(W1, W1Thi, W1Tlo, D_INK, D_HID);
    splitT_kernel<<<dim3(D_HID, D_CODE_ / 256), 256, 0, stream>>>(W2, W2Thi, W2Tlo, D_HID, D_CODE_);

    gemm1_kernel<<<dim3(M_ROWS / 128, D_HID / 128), 256, 0, stream>>>(
        x, W1Thi, W1Tlo, b1, h_hi, h_lo);
    gemm2_kernel<<<dim3(M_ROWS / 128, D_CODE_ / 128), 256, 0, stream>>>(
        h_hi, h_lo, W2Thi, W2Tlo, b2, enchi, enclo, accum);
    dist_kernel<<<M_ROWS / 128, 256, 0, stream>>>(
        enchi, enclo, cbhi, cblo, cbn, out, accum, cnt, list);
    fixup_kernel<<<256, 256, 0, stream>>>(x, W1, b1, W2, b2, cb, cbn, cnt, list, out);
    finalize_kernel<<<1, 1, 0, stream>>>(accum, out);
}